// Round 7
// baseline (161.225 us; speedup 1.0000x reference)
//
#include <hip/hip_runtime.h>
#include <cstdint>
#include <cstddef>

#define S_LEN 2048
#define DIN   512
#define DOUT  64
#define NB    4
#define NH    8

typedef __attribute__((ext_vector_type(8))) short bf16x8;
typedef __attribute__((ext_vector_type(4))) float f32x4;
typedef __attribute__((ext_vector_type(16))) float f32x16;

static __device__ __forceinline__ f32x4 mfma16(bf16x8 a, bf16x8 b, f32x4 c) {
    return __builtin_amdgcn_mfma_f32_16x16x32_bf16(a, b, c, 0, 0, 0);
}
static __device__ __forceinline__ f32x16 mfma32(bf16x8 a, bf16x8 b, f32x16 c) {
    return __builtin_amdgcn_mfma_f32_32x32x16_bf16(a, b, c, 0, 0, 0);
}

static __device__ __forceinline__ uint16_t f2bf(float x) {
    uint32_t u = __builtin_bit_cast(uint32_t, x);
    u += 0x7fffu + ((u >> 16) & 1u);
    return (uint16_t)(u >> 16);
}
static __device__ __forceinline__ float bf2f(uint16_t h) {
    uint32_t u = ((uint32_t)h) << 16;
    return __builtin_bit_cast(float, u);
}
static __device__ __forceinline__ uint32_t cvt_pk_bf16(float lo, float hi) {
    uint32_t r;
    asm("v_cvt_pk_bf16_f32 %0, %1, %2" : "=v"(r) : "v"(lo), "v"(hi));
    return r;
}

typedef const __attribute__((address_space(1))) void* as1p;
typedef __attribute__((address_space(3))) void* as3p;
static __device__ __forceinline__ void gload_lds16(const void* g, void* l) {
    __builtin_amdgcn_global_load_lds((as1p)g, (as3p)l, 16, 0, 0);
}

// ---------------------------------------------------------------------------
// Kernel 1: weight prep via LDS transpose (coalesced both sides).
// ---------------------------------------------------------------------------
__global__ __launch_bounds__(256) void prep_w(
    const float* __restrict__ w, const float* __restrict__ wo,
    uint16_t* __restrict__ whiT, uint16_t* __restrict__ wloT,
    uint16_t* __restrict__ woT)
{
    __shared__ float tile[64][65];
    const int blk = blockIdx.x;
    const int t = threadIdx.x;
    const int tq = t >> 6, tr = t & 63;

    if (blk < 192) {
        const int hp = blk >> 3, i0 = (blk & 7) * 64;
        const int p = hp % 3;
        const float s = (p == 0) ? 0.18033688011112042f : 1.0f; // 0.125*log2(e)
        const float* __restrict__ src = w + (size_t)hp * (DIN * DOUT);
        #pragma unroll
        for (int r = 0; r < 16; ++r) {
            const int ir = r * 4 + tq;
            tile[ir][tr] = src[(size_t)(i0 + ir) * DOUT + tr];
        }
        __syncthreads();
        uint16_t* __restrict__ dh = whiT + (size_t)hp * (DOUT * DIN);
        uint16_t* __restrict__ dl = wloT + (size_t)hp * (DOUT * DIN);
        #pragma unroll
        for (int r = 0; r < 16; ++r) {
            const int o = r * 4 + tq;
            const float v = tile[tr][o] * s;
            const uint16_t hi = f2bf(v);
            dh[(size_t)o * DIN + i0 + tr] = hi;
            dl[(size_t)o * DIN + i0 + tr] = f2bf(v - bf2f(hi));
        }
    } else {
        const int i0 = (blk - 192) * 64;
        #pragma unroll
        for (int r = 0; r < 16; ++r) {
            const int ir = r * 4 + tq;
            tile[ir][tr] = wo[(size_t)(i0 + ir) * DOUT + tr];
        }
        __syncthreads();
        #pragma unroll
        for (int r = 0; r < 16; ++r) {
            const int o = r * 4 + tq;
            woT[(size_t)o * DIN + i0 + tr] = f2bf(tile[tr][o]);
        }
    }
}

// ---------------------------------------------------------------------------
// Kernel 2: split x [8192][512] fp32 -> xhi/xlo bf16 (vectorized, one pass).
// ---------------------------------------------------------------------------
__global__ __launch_bounds__(256) void split_x(
    const float* __restrict__ x, uint16_t* __restrict__ xhi, uint16_t* __restrict__ xlo)
{
    const size_t idx = ((size_t)blockIdx.x * 256 + threadIdx.x) * 8;
    const float4 a = *(const float4*)(x + idx);
    const float4 b = *(const float4*)(x + idx + 4);
    const float xv[8] = {a.x, a.y, a.z, a.w, b.x, b.y, b.z, b.w};
    union { uint16_t u[8]; uint4 v; } H, L;
    #pragma unroll
    for (int j = 0; j < 8; ++j) {
        const uint16_t hi = f2bf(xv[j]);
        H.u[j] = hi;
        L.u[j] = f2bf(xv[j] - bf2f(hi));
    }
    *(uint4*)(xhi + idx) = H.v;
    *(uint4*)(xlo + idx) = L.v;
}

// ---------------------------------------------------------------------------
// Kernel 3: QKV projection GEMM (m97 structure). V written pre-transposed:
// vT[bh][d][s] (kills the standalone transpose kernel).
// ---------------------------------------------------------------------------
__global__ __launch_bounds__(256) void gemm_qkv(
    const uint16_t* __restrict__ xhi, const uint16_t* __restrict__ xlo,
    const uint16_t* __restrict__ whiT, const uint16_t* __restrict__ wloT,
    uint16_t* __restrict__ qhi, uint16_t* __restrict__ qlo,
    uint16_t* __restrict__ khi, uint16_t* __restrict__ klo,
    uint16_t* __restrict__ vT)
{
    __shared__ __align__(16) uint16_t lds[2 * 128 * 64];

    const int bid = blockIdx.x;
    const int xcd = bid & 7, wi = bid >> 3;
    const int mt = xcd * 8 + wi / 12, nt = wi % 12;
    const int m0 = mt * 128, n0 = nt * 128;
    const int tid = threadIdx.x;
    const int l = tid & 63, w = tid >> 6;
    const int g = l >> 4, lm = l & 15;
    const int wm = w >> 1, wn = w & 1;

    const f32x4 Z = {0.f, 0.f, 0.f, 0.f};
    f32x4 acc[4][4];
    #pragma unroll
    for (int a = 0; a < 4; ++a)
        #pragma unroll
        for (int b = 0; b < 4; ++b) acc[a][b] = Z;

    int srow[4], scol[4];
    #pragma unroll
    for (int i = 0; i < 4; ++i) {
        const int c = i * 256 + tid;
        srow[i] = c >> 3;
        scol[i] = ((c & 7) * 8) ^ ((srow[i] & 7) << 3);
    }

    for (int kt = 0; kt < 24; ++kt) {
        const int k0 = (kt & 7) * 64;
        const uint16_t* __restrict__ As = (kt < 16) ? xhi : xlo;
        const uint16_t* __restrict__ Bs = (kt >= 8 && kt < 16) ? wloT : whiT;
        #pragma unroll
        for (int i = 0; i < 4; ++i) {
            const int c8 = (i * 256 + tid) * 8;
            gload_lds16(As + (size_t)(m0 + srow[i]) * DIN + k0 + scol[i], &lds[c8]);
            gload_lds16(Bs + (size_t)(n0 + srow[i]) * DIN + k0 + scol[i], &lds[128 * 64 + c8]);
        }
        asm volatile("s_waitcnt vmcnt(0)" ::: "memory");
        __syncthreads();

        bf16x8 af[4][2];
        #pragma unroll
        for (int mi = 0; mi < 4; ++mi) {
            const int r = wm * 64 + mi * 16 + lm;
            const int rb = r * 128;
            #pragma unroll
            for (int kk = 0; kk < 2; ++kk) {
                const int cb = (kk * 64 + g * 16) ^ ((r & 7) << 4);
                af[mi][kk] = *(const bf16x8*)((const char*)lds + rb + cb);
            }
        }
        #pragma unroll
        for (int ni = 0; ni < 4; ++ni) {
            const int r = wn * 64 + ni * 16 + lm;
            const int rb = 128 * 64 * 2 + r * 128;
            bf16x8 bfr[2];
            #pragma unroll
            for (int kk = 0; kk < 2; ++kk) {
                const int cb = (kk * 64 + g * 16) ^ ((r & 7) << 4);
                bfr[kk] = *(const bf16x8*)((const char*)lds + rb + cb);
            }
            #pragma unroll
            for (int mi = 0; mi < 4; ++mi) {
                acc[mi][ni] = mfma16(af[mi][0], bfr[0], acc[mi][ni]);
                acc[mi][ni] = mfma16(af[mi][1], bfr[1], acc[mi][ni]);
            }
        }
        __syncthreads();
    }

    #pragma unroll
    for (int ni = 0; ni < 4; ++ni) {
        const int n = n0 + wn * 64 + ni * 16 + lm;
        const int hp = n >> 6, o = n & 63;
        const int h = hp / 3, p = hp - h * 3;
        if (p < 2) {
            uint16_t* __restrict__ dhi = (p == 0) ? qhi : khi;
            uint16_t* __restrict__ dlo = (p == 0) ? qlo : klo;
            #pragma unroll
            for (int mi = 0; mi < 4; ++mi) {
                #pragma unroll
                for (int j = 0; j < 4; ++j) {
                    const int m = m0 + wm * 64 + mi * 16 + 4 * g + j;
                    const int b = m >> 11, s = m & 2047;
                    const size_t idx = ((size_t)(b * NH + h) * S_LEN + s) * DOUT + o;
                    const float v = acc[mi][ni][j];
                    const uint16_t hi = f2bf(v);
                    dhi[idx] = hi;
                    dlo[idx] = f2bf(v - bf2f(hi));
                }
            }
        } else {
            #pragma unroll
            for (int mi = 0; mi < 4; ++mi) {
                const int m = m0 + wm * 64 + mi * 16 + 4 * g;  // 4 consecutive s
                const int b = m >> 11, s = m & 2047;
                uint2 val;
                val.x = cvt_pk_bf16(acc[mi][ni][0], acc[mi][ni][1]);
                val.y = cvt_pk_bf16(acc[mi][ni][2], acc[mi][ni][3]);
                *(uint2*)(vT + ((size_t)((b * NH + h) * DOUT + o)) * S_LEN + s) = val;
            }
        }
    }
}

// ---------------------------------------------------------------------------
// Kernel 4: flash attention, 32x32 MFMA, in-register softmax, no P-LDS.
//   FRAGMENT-MAJOR LDS: granule g holds lane (g&63)'s fragment slice for
//   subtile (g>>6); every ds_read_b128 is base + lane*16 + imm -> zero bank
//   conflicts, no swizzle math. Staging source (per-lane OK) does the
//   permutation: kr = ((c>>8)<<5)|(c&31), d0 = ((c>>5)&7)<<3.
//   R4/R6 counted-vmcnt no-drain pipeline retained (K dbuf + V single).
// ---------------------------------------------------------------------------
__global__ __launch_bounds__(256, 2) void attn_fwd(
    const uint16_t* __restrict__ qhi, const uint16_t* __restrict__ qlo,
    const uint16_t* __restrict__ khi, const uint16_t* __restrict__ klo,
    const uint16_t* __restrict__ vT, uint16_t* __restrict__ oc)
{
    __shared__ __align__(16) char smem[40960];
    // [0,16384): kbuf0 (khi 8K | klo 8K)  [16384,32768): kbuf1  [32768,40960): vbuf
    char* __restrict__ vbuf = smem + 32768;

    const int bid = blockIdx.x;
    const int qt = (bid >> 3) & 15, bh = (bid & 7) + 8 * (bid >> 7);
    const int tid = threadIdx.x;
    const int l = tid & 63, wq = tid >> 6;
    const int L = l >> 5, lq = l & 31;
    const size_t base = (size_t)bh * (S_LEN * DOUT);

    // fragment-major staging: chunk c -> LDS byte c*16; source granule:
    //   row  = ((c>>8)<<5) | (c&31)   (K row / V^T d-row)
    //   doff = ((c>>5)&7) << 3        (element offset within the 64-wide dim)
    const int c0 = tid, c1 = tid + 256;
    const int kr0 = c0 & 31,        do0 = ((c0 >> 5) & 7) << 3;
    const int kr1 = 32 + (c1 & 31), do1 = ((c1 >> 5) & 7) << 3;

    // Q B-fragments: lane holds Q[q = qrow][d = dsub*16 + 8L + j]
    const int qrow = qt * 128 + wq * 32 + lq;
    const uint16_t* qp  = qhi + base + (size_t)qrow * DOUT;
    const uint16_t* qlp = qlo + base + (size_t)qrow * DOUT;
    bf16x8 qh[4], qlf[4];
    #pragma unroll
    for (int dsub = 0; dsub < 4; ++dsub) {
        qh[dsub]  = *(const bf16x8*)(qp  + dsub * 16 + L * 8);
        qlf[dsub] = *(const bf16x8*)(qlp + dsub * 16 + L * 8);
    }

    f32x16 Zv;
    #pragma unroll
    for (int r = 0; r < 16; ++r) Zv[r] = 0.f;
    f32x16 Oa[2] = {Zv, Zv};           // O^T[d = dh*32 + row(reg,L)][q = lq]
    float m_run = -INFINITY, l_run = 0.f;

    // prologue: K(0) -> kbuf0 (4 outstanding)
    gload_lds16(khi + base + (size_t)kr0 * DOUT + do0, smem + c0 * 16);
    gload_lds16(khi + base + (size_t)kr1 * DOUT + do1, smem + c1 * 16);
    gload_lds16(klo + base + (size_t)kr0 * DOUT + do0, smem + 8192 + c0 * 16);
    gload_lds16(klo + base + (size_t)kr1 * DOUT + do1, smem + 8192 + c1 * 16);

    for (int kt = 0; kt < 32; ++kt) {
        const int cur = kt & 1;
        char* __restrict__ kb = smem + cur * 16384;
        const int s0 = kt * 64;

        // [A] issue V(kt) then K(kt+1) (dummy tile 0 on last iter)
        gload_lds16(vT + base + (size_t)kr0 * S_LEN + s0 + do0, vbuf + c0 * 16);
        gload_lds16(vT + base + (size_t)kr1 * S_LEN + s0 + do1, vbuf + c1 * 16);
        {
            char* __restrict__ kn = smem + (cur ^ 1) * 16384;
            const int sn = (kt < 31) ? s0 + 64 : 0;
            gload_lds16(khi + base + (size_t)(sn + kr0) * DOUT + do0, kn + c0 * 16);
            gload_lds16(khi + base + (size_t)(sn + kr1) * DOUT + do1, kn + c1 * 16);
            gload_lds16(klo + base + (size_t)(sn + kr0) * DOUT + do0, kn + 8192 + c0 * 16);
            gload_lds16(klo + base + (size_t)(sn + kr1) * DOUT + do1, kn + 8192 + c1 * 16);
        }
        // K(kt) resident (retire oldest 4 of 10); V + K(next) in flight
        asm volatile("s_waitcnt vmcnt(6)" ::: "memory");
        __builtin_amdgcn_s_barrier();
        __builtin_amdgcn_sched_barrier(0);

        // [B] QK^T: sa[ks] holds S[k = ks*32 + (reg&3)+8(reg>>2)+4L][q = lq]
        //   fragment read = base + lane*16 + imm (conflict-free sequential)
        f32x16 sa[2];
        __builtin_amdgcn_s_setprio(1);
        #pragma unroll
        for (int ks = 0; ks < 2; ++ks) {
            f32x16 s = Zv;
            #pragma unroll
            for (int dsub = 0; dsub < 4; ++dsub) {
                const uint32_t off = (uint32_t)(((ks * 4 + dsub) << 10) + (l << 4));
                const bf16x8 kh = *(const bf16x8*)(kb + off);
                const bf16x8 kl = *(const bf16x8*)(kb + 8192 + off);
                s = mfma32(kh, qh[dsub], s);
                s = mfma32(kh, qlf[dsub], s);
                s = mfma32(kl, qh[dsub], s);
            }
            sa[ks] = s;
        }
        __builtin_amdgcn_s_setprio(0);

        // ---- softmax: all 32 in-lane values are the SAME q-row
        float pmax = sa[0][0];
        #pragma unroll
        for (int ks = 0; ks < 2; ++ks)
            #pragma unroll
            for (int r = 0; r < 16; ++r) pmax = fmaxf(pmax, sa[ks][r]);
        pmax = fmaxf(pmax, __shfl_xor(pmax, 32));

        if (!__all(pmax - m_run <= 8.f)) {
            const float m_new = fmaxf(m_run, pmax);
            const float alpha = __builtin_amdgcn_exp2f(m_run - m_new);
            m_run = m_new;
            #pragma unroll
            for (int r = 0; r < 16; ++r) { Oa[0][r] *= alpha; Oa[1][r] *= alpha; }
            l_run *= alpha;
        }

        float lsum = 0.f;
        #pragma unroll
        for (int ks = 0; ks < 2; ++ks)
            #pragma unroll
            for (int r = 0; r < 16; ++r) {
                const float pv = __builtin_amdgcn_exp2f(sa[ks][r] - m_run);
                sa[ks][r] = pv;
                lsum += pv;
            }
        lsum += __shfl_xor(lsum, 32);
        l_run += lsum;

        // ---- pack P into PV B-fragments: pfrag[kc] = P[k = kc*16 + 8L + j][q]
        // permlane32_swap(VDST=lo_pack, VSRC=hi_pack)
        bf16x8 pfrag[4];
        #pragma unroll
        for (int ks = 0; ks < 2; ++ks) {
            uint32_t a0 = cvt_pk_bf16(sa[ks][0], sa[ks][1]);
            uint32_t a1 = cvt_pk_bf16(sa[ks][2], sa[ks][3]);
            uint32_t a2 = cvt_pk_bf16(sa[ks][4], sa[ks][5]);
            uint32_t a3 = cvt_pk_bf16(sa[ks][6], sa[ks][7]);
            asm volatile("v_permlane32_swap_b32 %0, %1" : "+v"(a0), "+v"(a2));
            asm volatile("v_permlane32_swap_b32 %0, %1" : "+v"(a1), "+v"(a3));
            union { uint32_t w[4]; bf16x8 v; } u;
            u.w[0] = a0; u.w[1] = a1; u.w[2] = a2; u.w[3] = a3;
            pfrag[2 * ks] = u.v;
            uint32_t b0 = cvt_pk_bf16(sa[ks][8],  sa[ks][9]);
            uint32_t b1 = cvt_pk_bf16(sa[ks][10], sa[ks][11]);
            uint32_t b2 = cvt_pk_bf16(sa[ks][12], sa[ks][13]);
            uint32_t b3 = cvt_pk_bf16(sa[ks][14], sa[ks][15]);
            asm volatile("v_permlane32_swap_b32 %0, %1" : "+v"(b0), "+v"(b2));
            asm volatile("v_permlane32_swap_b32 %0, %1" : "+v"(b1), "+v"(b3));
            union { uint32_t w[4]; bf16x8 v; } u2;
            u2.w[0] = b0; u2.w[1] = b1; u2.w[2] = b2; u2.w[3] = b3;
            pfrag[2 * ks + 1] = u2.v;
        }

        // [C] V(kt) resident (retire oldest 2 of 6); K(kt+1) stays in flight
        asm volatile("s_waitcnt vmcnt(4)" ::: "memory");
        __builtin_amdgcn_s_barrier();
        __builtin_amdgcn_sched_barrier(0);

        // [D] PV: O^T[d][q] += V^T-frag . pfrag (fragment-major, seq reads)
        __builtin_amdgcn_s_setprio(1);
        #pragma unroll
        for (int dh = 0; dh < 2; ++dh) {
            #pragma unroll
            for (int kc = 0; kc < 4; ++kc) {
                const uint32_t off = (uint32_t)(((dh * 4 + kc) << 10) + (l << 4));
                const bf16x8 vv = *(const bf16x8*)(vbuf + off);
                Oa[dh] = mfma32(vv, pfrag[kc], Oa[dh]);
            }
        }
        __builtin_amdgcn_s_setprio(0);

        // [E] protect vbuf/kbuf from next iter's DMA; NO vmcnt drain
        __builtin_amdgcn_s_barrier();
        __builtin_amdgcn_sched_barrier(0);
    }

    // epilogue: lane-local normalize; O^T -> oc[b][s][h*64+d], 8B packed
    const int b = bh >> 3, hh = bh & 7;
    const float li = 1.f / l_run;
    const int srow = qt * 128 + wq * 32 + lq;
    const size_t rbase = ((size_t)b * S_LEN + srow) * (NH * DOUT) + hh * DOUT;
    #pragma unroll
    for (int dh = 0; dh < 2; ++dh) {
        #pragma unroll
        for (int rq = 0; rq < 4; ++rq) {
            const int d0 = dh * 32 + rq * 8 + L * 4;
            uint2 val;
            val.x = cvt_pk_bf16(Oa[dh][rq * 4 + 0] * li, Oa[dh][rq * 4 + 1] * li);
            val.y = cvt_pk_bf16(Oa[dh][rq * 4 + 2] * li, Oa[dh][rq * 4 + 3] * li);
            *(uint2*)(oc + rbase + d0) = val;
        }
    }
}

// ---------------------------------------------------------------------------
// Kernel 5: output projection out = o_concat[8192x512] @ wo[512x64], fp32 out.
// ---------------------------------------------------------------------------
__global__ __launch_bounds__(256) void oproj(
    const uint16_t* __restrict__ oc, const uint16_t* __restrict__ woT,
    float* __restrict__ out)
{
    const int mt = blockIdx.x;
    const int tid = threadIdx.x;
    const int l = tid & 63, w = tid >> 6;
    const int g = l >> 4, lm = l & 15;
    const int m0 = mt * 64 + w * 16;
    const f32x4 Z = {0.f, 0.f, 0.f, 0.f};
    f32x4 acc[4] = {Z, Z, Z, Z};
    const uint16_t* __restrict__ arow = oc + (size_t)(m0 + lm) * (NH * DOUT);
    for (int kc = 0; kc < 16; ++kc) {
        const bf16x8 a = *(const bf16x8*)(arow + kc * 32 + g * 8);
        #pragma unroll
        for (int nt = 0; nt < 4; ++nt) {
            const bf16x8 bfr = *(const bf16x8*)(woT + (size_t)(nt * 16 + lm) * (NH * DOUT) + kc * 32 + g * 8);
            acc[nt] = mfma16(a, bfr, acc[nt]);
        }
    }
    #pragma unroll
    for (int nt = 0; nt < 4; ++nt)
        #pragma unroll
        for (int j = 0; j < 4; ++j)
            out[(size_t)(m0 + 4 * g + j) * DOUT + nt * 16 + lm] = acc[nt][j];
}

// ---------------------------------------------------------------------------
extern "C" void kernel_launch(void* const* d_in, const int* in_sizes, int n_in,
                              void* d_out, int out_size, void* d_ws, size_t ws_size,
                              hipStream_t stream) {
    const float* x  = (const float*)d_in[0];
    const float* w  = (const float*)d_in[1];
    const float* wo = (const float*)d_in[2];
    float* out = (float*)d_out;

    char* ws = (char*)d_ws;
    uint16_t* qhi  = (uint16_t*)(ws);              // 8388608 B each
    uint16_t* qlo  = (uint16_t*)(ws + 8388608);
    uint16_t* khi  = (uint16_t*)(ws + 16777216);
    uint16_t* klo  = (uint16_t*)(ws + 25165824);
    uint16_t* vT   = (uint16_t*)(ws + 33554432);   // [B*H][64][2048] bf16
    uint16_t* xhi  = (uint16_t*)(ws + 41943040);   // 8388608 B
    uint16_t* xlo  = (uint16_t*)(ws + 50331648);   // 8388608 B
    uint16_t* whiT = (uint16_t*)(ws + 58720256);   // 1572864 B
    uint16_t* wloT = (uint16_t*)(ws + 60293120);
    uint16_t* woT  = (uint16_t*)(ws + 61865984);   // 65536 B
    // oc aliases xhi (dead after gemm_qkv; split_x rewrites it every call).
    uint16_t* oc   = xhi;

    hipLaunchKernelGGL(prep_w, dim3(200), dim3(256), 0, stream, w, wo, whiT, wloT, woT);
    hipLaunchKernelGGL(split_x, dim3(2048), dim3(256), 0, stream, x, xhi, xlo);
    hipLaunchKernelGGL(gemm_qkv, dim3(768), dim3(256), 0, stream,
                       xhi, xlo, whiT, wloT, qhi, qlo, khi, klo, vT);
    hipLaunchKernelGGL(attn_fwd, dim3(512), dim3(256), 0, stream,
                       qhi, qlo, khi, klo, vT, oc);
    hipLaunchKernelGGL(oproj, dim3(128), dim3(256), 0, stream, oc, woT, out);
}

// Round 8
// 160.666 us; speedup vs baseline: 1.0035x; 1.0035x over previous
//
#include <hip/hip_runtime.h>
#include <cstdint>
#include <cstddef>

#define S_LEN 2048
#define DIN   512
#define DOUT  64
#define NB    4
#define NH    8

typedef __attribute__((ext_vector_type(8))) short bf16x8;
typedef __attribute__((ext_vector_type(4))) float f32x4;
typedef __attribute__((ext_vector_type(16))) float f32x16;

static __device__ __forceinline__ f32x4 mfma16(bf16x8 a, bf16x8 b, f32x4 c) {
    return __builtin_amdgcn_mfma_f32_16x16x32_bf16(a, b, c, 0, 0, 0);
}
static __device__ __forceinline__ f32x16 mfma32(bf16x8 a, bf16x8 b, f32x16 c) {
    return __builtin_amdgcn_mfma_f32_32x32x16_bf16(a, b, c, 0, 0, 0);
}

static __device__ __forceinline__ uint16_t f2bf(float x) {
    uint32_t u = __builtin_bit_cast(uint32_t, x);
    u += 0x7fffu + ((u >> 16) & 1u);
    return (uint16_t)(u >> 16);
}
static __device__ __forceinline__ float bf2f(uint16_t h) {
    uint32_t u = ((uint32_t)h) << 16;
    return __builtin_bit_cast(float, u);
}
static __device__ __forceinline__ uint32_t cvt_pk_bf16(float lo, float hi) {
    uint32_t r;
    asm("v_cvt_pk_bf16_f32 %0, %1, %2" : "=v"(r) : "v"(lo), "v"(hi));
    return r;
}

typedef const __attribute__((address_space(1))) void* as1p;
typedef __attribute__((address_space(3))) void* as3p;
static __device__ __forceinline__ void gload_lds16(const void* g, void* l) {
    __builtin_amdgcn_global_load_lds((as1p)g, (as3p)l, 16, 0, 0);
}

// ---------------------------------------------------------------------------
// Kernel 1: weight prep via LDS transpose (coalesced both sides).
// ---------------------------------------------------------------------------
__global__ __launch_bounds__(256) void prep_w(
    const float* __restrict__ w, const float* __restrict__ wo,
    uint16_t* __restrict__ whiT, uint16_t* __restrict__ wloT,
    uint16_t* __restrict__ woT)
{
    __shared__ float tile[64][65];
    const int blk = blockIdx.x;
    const int t = threadIdx.x;
    const int tq = t >> 6, tr = t & 63;

    if (blk < 192) {
        const int hp = blk >> 3, i0 = (blk & 7) * 64;
        const int p = hp % 3;
        const float s = (p == 0) ? 0.18033688011112042f : 1.0f; // 0.125*log2(e)
        const float* __restrict__ src = w + (size_t)hp * (DIN * DOUT);
        #pragma unroll
        for (int r = 0; r < 16; ++r) {
            const int ir = r * 4 + tq;
            tile[ir][tr] = src[(size_t)(i0 + ir) * DOUT + tr];
        }
        __syncthreads();
        uint16_t* __restrict__ dh = whiT + (size_t)hp * (DOUT * DIN);
        uint16_t* __restrict__ dl = wloT + (size_t)hp * (DOUT * DIN);
        #pragma unroll
        for (int r = 0; r < 16; ++r) {
            const int o = r * 4 + tq;
            const float v = tile[tr][o] * s;
            const uint16_t hi = f2bf(v);
            dh[(size_t)o * DIN + i0 + tr] = hi;
            dl[(size_t)o * DIN + i0 + tr] = f2bf(v - bf2f(hi));
        }
    } else {
        const int i0 = (blk - 192) * 64;
        #pragma unroll
        for (int r = 0; r < 16; ++r) {
            const int ir = r * 4 + tq;
            tile[ir][tr] = wo[(size_t)(i0 + ir) * DOUT + tr];
        }
        __syncthreads();
        #pragma unroll
        for (int r = 0; r < 16; ++r) {
            const int o = r * 4 + tq;
            woT[(size_t)o * DIN + i0 + tr] = f2bf(tile[tr][o]);
        }
    }
}

// ---------------------------------------------------------------------------
// Kernel 2: split x [8192][512] fp32 -> xhi/xlo bf16 (vectorized, one pass).
// ---------------------------------------------------------------------------
__global__ __launch_bounds__(256) void split_x(
    const float* __restrict__ x, uint16_t* __restrict__ xhi, uint16_t* __restrict__ xlo)
{
    const size_t idx = ((size_t)blockIdx.x * 256 + threadIdx.x) * 8;
    const float4 a = *(const float4*)(x + idx);
    const float4 b = *(const float4*)(x + idx + 4);
    const float xv[8] = {a.x, a.y, a.z, a.w, b.x, b.y, b.z, b.w};
    union { uint16_t u[8]; uint4 v; } H, L;
    #pragma unroll
    for (int j = 0; j < 8; ++j) {
        const uint16_t hi = f2bf(xv[j]);
        H.u[j] = hi;
        L.u[j] = f2bf(xv[j] - bf2f(hi));
    }
    *(uint4*)(xhi + idx) = H.v;
    *(uint4*)(xlo + idx) = L.v;
}

// ---------------------------------------------------------------------------
// Kernel 3: QKV projection GEMM (m97 structure). V written pre-transposed:
// vT[bh][d][s] (kills the standalone transpose kernel).
// ---------------------------------------------------------------------------
__global__ __launch_bounds__(256) void gemm_qkv(
    const uint16_t* __restrict__ xhi, const uint16_t* __restrict__ xlo,
    const uint16_t* __restrict__ whiT, const uint16_t* __restrict__ wloT,
    uint16_t* __restrict__ qhi, uint16_t* __restrict__ qlo,
    uint16_t* __restrict__ khi, uint16_t* __restrict__ klo,
    uint16_t* __restrict__ vT)
{
    __shared__ __align__(16) uint16_t lds[2 * 128 * 64];

    const int bid = blockIdx.x;
    const int xcd = bid & 7, wi = bid >> 3;
    const int mt = xcd * 8 + wi / 12, nt = wi % 12;
    const int m0 = mt * 128, n0 = nt * 128;
    const int tid = threadIdx.x;
    const int l = tid & 63, w = tid >> 6;
    const int g = l >> 4, lm = l & 15;
    const int wm = w >> 1, wn = w & 1;

    const f32x4 Z = {0.f, 0.f, 0.f, 0.f};
    f32x4 acc[4][4];
    #pragma unroll
    for (int a = 0; a < 4; ++a)
        #pragma unroll
        for (int b = 0; b < 4; ++b) acc[a][b] = Z;

    int srow[4], scol[4];
    #pragma unroll
    for (int i = 0; i < 4; ++i) {
        const int c = i * 256 + tid;
        srow[i] = c >> 3;
        scol[i] = ((c & 7) * 8) ^ ((srow[i] & 7) << 3);
    }

    for (int kt = 0; kt < 24; ++kt) {
        const int k0 = (kt & 7) * 64;
        const uint16_t* __restrict__ As = (kt < 16) ? xhi : xlo;
        const uint16_t* __restrict__ Bs = (kt >= 8 && kt < 16) ? wloT : whiT;
        #pragma unroll
        for (int i = 0; i < 4; ++i) {
            const int c8 = (i * 256 + tid) * 8;
            gload_lds16(As + (size_t)(m0 + srow[i]) * DIN + k0 + scol[i], &lds[c8]);
            gload_lds16(Bs + (size_t)(n0 + srow[i]) * DIN + k0 + scol[i], &lds[128 * 64 + c8]);
        }
        asm volatile("s_waitcnt vmcnt(0)" ::: "memory");
        __syncthreads();

        bf16x8 af[4][2];
        #pragma unroll
        for (int mi = 0; mi < 4; ++mi) {
            const int r = wm * 64 + mi * 16 + lm;
            const int rb = r * 128;
            #pragma unroll
            for (int kk = 0; kk < 2; ++kk) {
                const int cb = (kk * 64 + g * 16) ^ ((r & 7) << 4);
                af[mi][kk] = *(const bf16x8*)((const char*)lds + rb + cb);
            }
        }
        #pragma unroll
        for (int ni = 0; ni < 4; ++ni) {
            const int r = wn * 64 + ni * 16 + lm;
            const int rb = 128 * 64 * 2 + r * 128;
            bf16x8 bfr[2];
            #pragma unroll
            for (int kk = 0; kk < 2; ++kk) {
                const int cb = (kk * 64 + g * 16) ^ ((r & 7) << 4);
                bfr[kk] = *(const bf16x8*)((const char*)lds + rb + cb);
            }
            #pragma unroll
            for (int mi = 0; mi < 4; ++mi) {
                acc[mi][ni] = mfma16(af[mi][0], bfr[0], acc[mi][ni]);
                acc[mi][ni] = mfma16(af[mi][1], bfr[1], acc[mi][ni]);
            }
        }
        __syncthreads();
    }

    #pragma unroll
    for (int ni = 0; ni < 4; ++ni) {
        const int n = n0 + wn * 64 + ni * 16 + lm;
        const int hp = n >> 6, o = n & 63;
        const int h = hp / 3, p = hp - h * 3;
        if (p < 2) {
            uint16_t* __restrict__ dhi = (p == 0) ? qhi : khi;
            uint16_t* __restrict__ dlo = (p == 0) ? qlo : klo;
            #pragma unroll
            for (int mi = 0; mi < 4; ++mi) {
                #pragma unroll
                for (int j = 0; j < 4; ++j) {
                    const int m = m0 + wm * 64 + mi * 16 + 4 * g + j;
                    const int b = m >> 11, s = m & 2047;
                    const size_t idx = ((size_t)(b * NH + h) * S_LEN + s) * DOUT + o;
                    const float v = acc[mi][ni][j];
                    const uint16_t hi = f2bf(v);
                    dhi[idx] = hi;
                    dlo[idx] = f2bf(v - bf2f(hi));
                }
            }
        } else {
            #pragma unroll
            for (int mi = 0; mi < 4; ++mi) {
                const int m = m0 + wm * 64 + mi * 16 + 4 * g;  // 4 consecutive s
                const int b = m >> 11, s = m & 2047;
                uint2 val;
                val.x = cvt_pk_bf16(acc[mi][ni][0], acc[mi][ni][1]);
                val.y = cvt_pk_bf16(acc[mi][ni][2], acc[mi][ni][3]);
                *(uint2*)(vT + ((size_t)((b * NH + h) * DOUT + o)) * S_LEN + s) = val;
            }
        }
    }
}

// ---------------------------------------------------------------------------
// Kernel 4: flash attention, 32x32 MFMA, in-register softmax, fragment-major
//   LDS (zero bank conflicts), PIPELINED: iter kt runs QK(kt+1) [MFMA] in
//   parallel with softmax(kt) [VALU/TRANS] (no data dep -> scheduler
//   interleaves; T15). K 2-ahead prefetch (dbuf), V dbuf. ONE vmcnt(0) + ONE
//   barrier per iter (nothing newer in flight at the wait point).
//   LDS 48KB: kbuf0/1 (16KB: khi|klo) + vbuf0/1 (8KB each).
// ---------------------------------------------------------------------------
__global__ __launch_bounds__(256, 2) void attn_fwd(
    const uint16_t* __restrict__ qhi, const uint16_t* __restrict__ qlo,
    const uint16_t* __restrict__ khi, const uint16_t* __restrict__ klo,
    const uint16_t* __restrict__ vT, uint16_t* __restrict__ oc)
{
    __shared__ __align__(16) char smem[49152];
    char* __restrict__ vbufs = smem + 32768;   // vbuf0 | vbuf1 (8KB each)

    const int bid = blockIdx.x;
    const int qt = (bid >> 3) & 15, bh = (bid & 7) + 8 * (bid >> 7);
    const int tid = threadIdx.x;
    const int l = tid & 63, wq = tid >> 6;
    const int L = l >> 5, lq = l & 31;
    const size_t base = (size_t)bh * (S_LEN * DOUT);

    // fragment-major staging: chunk c -> LDS byte c*16; source granule:
    //   row  = ((c>>8)<<5) | (c&31), doff = ((c>>5)&7) << 3
    const int c0 = tid, c1 = tid + 256;
    const int kr0 = c0 & 31,        do0 = ((c0 >> 5) & 7) << 3;
    const int kr1 = 32 + (c1 & 31), do1 = ((c1 >> 5) & 7) << 3;

    // Q B-fragments: lane holds Q[q = qrow][d = dsub*16 + 8L + j]
    const int qrow = qt * 128 + wq * 32 + lq;
    const uint16_t* qp  = qhi + base + (size_t)qrow * DOUT;
    const uint16_t* qlp = qlo + base + (size_t)qrow * DOUT;
    bf16x8 qh[4], qlf[4];
    #pragma unroll
    for (int dsub = 0; dsub < 4; ++dsub) {
        qh[dsub]  = *(const bf16x8*)(qp  + dsub * 16 + L * 8);
        qlf[dsub] = *(const bf16x8*)(qlp + dsub * 16 + L * 8);
    }

    f32x16 Zv;
    #pragma unroll
    for (int r = 0; r < 16; ++r) Zv[r] = 0.f;
    f32x16 Oa[2] = {Zv, Zv};           // O^T[d = dh*32 + row(reg,L)][q = lq]
    float m_run = -INFINITY, l_run = 0.f;

    // QK compute (pure MFMA) from a K buffer into dst score regs
    auto qk_step = [&](const char* kb2, f32x16* dst) {
        #pragma unroll
        for (int ks = 0; ks < 2; ++ks) {
            f32x16 s = Zv;
            #pragma unroll
            for (int dsub = 0; dsub < 4; ++dsub) {
                const uint32_t off = (uint32_t)(((ks * 4 + dsub) << 10) + (l << 4));
                const bf16x8 kh = *(const bf16x8*)(kb2 + off);
                const bf16x8 kl = *(const bf16x8*)(kb2 + 8192 + off);
                s = mfma32(kh, qh[dsub], s);
                s = mfma32(kh, qlf[dsub], s);
                s = mfma32(kl, qh[dsub], s);
            }
            dst[ks] = s;
        }
    };

    // prologue: K(0)->kbuf0, K(1)->kbuf1, V(0)->vbuf0
    gload_lds16(khi + base + (size_t)kr0 * DOUT + do0, smem + c0 * 16);
    gload_lds16(khi + base + (size_t)kr1 * DOUT + do1, smem + c1 * 16);
    gload_lds16(klo + base + (size_t)kr0 * DOUT + do0, smem + 8192 + c0 * 16);
    gload_lds16(klo + base + (size_t)kr1 * DOUT + do1, smem + 8192 + c1 * 16);
    gload_lds16(khi + base + (size_t)(64 + kr0) * DOUT + do0, smem + 16384 + c0 * 16);
    gload_lds16(khi + base + (size_t)(64 + kr1) * DOUT + do1, smem + 16384 + c1 * 16);
    gload_lds16(klo + base + (size_t)(64 + kr0) * DOUT + do0, smem + 24576 + c0 * 16);
    gload_lds16(klo + base + (size_t)(64 + kr1) * DOUT + do1, smem + 24576 + c1 * 16);
    gload_lds16(vT + base + (size_t)kr0 * S_LEN + do0, vbufs + c0 * 16);
    gload_lds16(vT + base + (size_t)kr1 * S_LEN + do1, vbufs + c1 * 16);
    asm volatile("s_waitcnt vmcnt(0)" ::: "memory");
    __builtin_amdgcn_s_barrier();
    __builtin_amdgcn_sched_barrier(0);

    f32x16 saA[2], saB[2];
    qk_step(smem, saA);                // QK(0) from kbuf0

    // iter kt: sa holds QK(kt); computes QK(kt+1)->sb ∥ softmax(kt); PV(kt).
    auto iter = [&](int kt, f32x16* sa, f32x16* sb) {
        // [a] everything issued last iter (K(kt+1), V(kt)) resident
        asm volatile("s_waitcnt vmcnt(0)" ::: "memory");
        __builtin_amdgcn_s_barrier();
        __builtin_amdgcn_sched_barrier(0);

        // [b] DMA: K(kt+2) -> kbuf[kt&1], V(kt+1) -> vbuf[(kt+1)&1]
        {
            char* __restrict__ kn = smem + (kt & 1) * 16384;
            const int sK = (kt < 30) ? (kt + 2) * 64 : 0;
            gload_lds16(khi + base + (size_t)(sK + kr0) * DOUT + do0, kn + c0 * 16);
            gload_lds16(khi + base + (size_t)(sK + kr1) * DOUT + do1, kn + c1 * 16);
            gload_lds16(klo + base + (size_t)(sK + kr0) * DOUT + do0, kn + 8192 + c0 * 16);
            gload_lds16(klo + base + (size_t)(sK + kr1) * DOUT + do1, kn + 8192 + c1 * 16);
            char* __restrict__ vn = vbufs + ((kt + 1) & 1) * 8192;
            const int sV = (kt < 31) ? (kt + 1) * 64 : 0;
            gload_lds16(vT + base + (size_t)kr0 * S_LEN + sV + do0, vn + c0 * 16);
            gload_lds16(vT + base + (size_t)kr1 * S_LEN + sV + do1, vn + c1 * 16);
        }

        // [c] QK(kt+1) -> sb (MFMA)  ∥  softmax(kt) on sa (VALU/TRANS).
        //     Independent chains; scheduler interleaves.
        qk_step(smem + ((kt + 1) & 1) * 16384, sb);

        float m01 = fmaxf(sa[0][0], sa[0][1]);
        #pragma unroll
        for (int r = 2; r < 16; r += 2)
            m01 = fmaxf(m01, fmaxf(sa[0][r], sa[0][r + 1]));
        float m23 = fmaxf(sa[1][0], sa[1][1]);
        #pragma unroll
        for (int r = 2; r < 16; r += 2)
            m23 = fmaxf(m23, fmaxf(sa[1][r], sa[1][r + 1]));
        float pmax = fmaxf(m01, m23);
        pmax = fmaxf(pmax, __shfl_xor(pmax, 32));

        if (!__all(pmax - m_run <= 8.f)) {
            const float m_new = fmaxf(m_run, pmax);
            const float alpha = __builtin_amdgcn_exp2f(m_run - m_new);
            m_run = m_new;
            #pragma unroll
            for (int r = 0; r < 16; ++r) { Oa[0][r] *= alpha; Oa[1][r] *= alpha; }
            l_run *= alpha;
        }

        float lsum = 0.f;
        #pragma unroll
        for (int ks = 0; ks < 2; ++ks)
            #pragma unroll
            for (int r = 0; r < 16; ++r) {
                const float pv = __builtin_amdgcn_exp2f(sa[ks][r] - m_run);
                sa[ks][r] = pv;
                lsum += pv;
            }
        lsum += __shfl_xor(lsum, 32);
        l_run += lsum;

        // pack P into PV B-fragments (cvt_pk + permlane32_swap, VDST=lo pack)
        bf16x8 pfrag[4];
        #pragma unroll
        for (int ks = 0; ks < 2; ++ks) {
            uint32_t a0 = cvt_pk_bf16(sa[ks][0], sa[ks][1]);
            uint32_t a1 = cvt_pk_bf16(sa[ks][2], sa[ks][3]);
            uint32_t a2 = cvt_pk_bf16(sa[ks][4], sa[ks][5]);
            uint32_t a3 = cvt_pk_bf16(sa[ks][6], sa[ks][7]);
            asm volatile("v_permlane32_swap_b32 %0, %1" : "+v"(a0), "+v"(a2));
            asm volatile("v_permlane32_swap_b32 %0, %1" : "+v"(a1), "+v"(a3));
            union { uint32_t w[4]; bf16x8 v; } u;
            u.w[0] = a0; u.w[1] = a1; u.w[2] = a2; u.w[3] = a3;
            pfrag[2 * ks] = u.v;
            uint32_t b0 = cvt_pk_bf16(sa[ks][8],  sa[ks][9]);
            uint32_t b1 = cvt_pk_bf16(sa[ks][10], sa[ks][11]);
            uint32_t b2 = cvt_pk_bf16(sa[ks][12], sa[ks][13]);
            uint32_t b3 = cvt_pk_bf16(sa[ks][14], sa[ks][15]);
            asm volatile("v_permlane32_swap_b32 %0, %1" : "+v"(b0), "+v"(b2));
            asm volatile("v_permlane32_swap_b32 %0, %1" : "+v"(b1), "+v"(b3));
            union { uint32_t w[4]; bf16x8 v; } u2;
            u2.w[0] = b0; u2.w[1] = b1; u2.w[2] = b2; u2.w[3] = b3;
            pfrag[2 * ks + 1] = u2.v;
        }

        // [d] PV(kt) from vbuf[kt&1] (fragment-major, conflict-free)
        const char* __restrict__ vb = vbufs + (kt & 1) * 8192;
        __builtin_amdgcn_s_setprio(1);
        #pragma unroll
        for (int dh = 0; dh < 2; ++dh) {
            #pragma unroll
            for (int kc = 0; kc < 4; ++kc) {
                const uint32_t off = (uint32_t)(((dh * 4 + kc) << 10) + (l << 4));
                const bf16x8 vv = *(const bf16x8*)(vb + off);
                Oa[dh] = mfma32(vv, pfrag[kc], Oa[dh]);
            }
        }
        __builtin_amdgcn_s_setprio(0);
    };

    for (int kt2 = 0; kt2 < 16; ++kt2) {
        iter(2 * kt2,     saA, saB);
        iter(2 * kt2 + 1, saB, saA);
    }
    asm volatile("s_waitcnt vmcnt(0)" ::: "memory");

    // epilogue: lane-local normalize; O^T -> oc[b][s][h*64+d], 8B packed
    const int b = bh >> 3, hh = bh & 7;
    const float li = 1.f / l_run;
    const int srow = qt * 128 + wq * 32 + lq;
    const size_t rbase = ((size_t)b * S_LEN + srow) * (NH * DOUT) + hh * DOUT;
    #pragma unroll
    for (int dh = 0; dh < 2; ++dh) {
        #pragma unroll
        for (int rq = 0; rq < 4; ++rq) {
            const int d0 = dh * 32 + rq * 8 + L * 4;
            uint2 val;
            val.x = cvt_pk_bf16(Oa[dh][rq * 4 + 0] * li, Oa[dh][rq * 4 + 1] * li);
            val.y = cvt_pk_bf16(Oa[dh][rq * 4 + 2] * li, Oa[dh][rq * 4 + 3] * li);
            *(uint2*)(oc + rbase + d0) = val;
        }
    }
}

// ---------------------------------------------------------------------------
// Kernel 5: output projection out = o_concat[8192x512] @ wo[512x64], fp32 out.
// ---------------------------------------------------------------------------
__global__ __launch_bounds__(256) void oproj(
    const uint16_t* __restrict__ oc, const uint16_t* __restrict__ woT,
    float* __restrict__ out)
{
    const int mt = blockIdx.x;
    const int tid = threadIdx.x;
    const int l = tid & 63, w = tid >> 6;
    const int g = l >> 4, lm = l & 15;
    const int m0 = mt * 64 + w * 16;
    const f32x4 Z = {0.f, 0.f, 0.f, 0.f};
    f32x4 acc[4] = {Z, Z, Z, Z};
    const uint16_t* __restrict__ arow = oc + (size_t)(m0 + lm) * (NH * DOUT);
    for (int kc = 0; kc < 16; ++kc) {
        const bf16x8 a = *(const bf16x8*)(arow + kc * 32 + g * 8);
        #pragma unroll
        for (int nt = 0; nt < 4; ++nt) {
            const bf16x8 bfr = *(const bf16x8*)(woT + (size_t)(nt * 16 + lm) * (NH * DOUT) + kc * 32 + g * 8);
            acc[nt] = mfma16(a, bfr, acc[nt]);
        }
    }
    #pragma unroll
    for (int nt = 0; nt < 4; ++nt)
        #pragma unroll
        for (int j = 0; j < 4; ++j)
            out[(size_t)(m0 + 4 * g + j) * DOUT + nt * 16 + lm] = acc[nt][j];
}

// ---------------------------------------------------------------------------
extern "C" void kernel_launch(void* const* d_in, const int* in_sizes, int n_in,
                              void* d_out, int out_size, void* d_ws, size_t ws_size,
                              hipStream_t stream) {
    const float* x  = (const float*)d_in[0];
    const float* w  = (const float*)d_in[1];
    const float* wo = (const float*)d_in[2];
    float* out = (float*)d_out;

    char* ws = (char*)d_ws;
    uint16_t* qhi  = (uint16_t*)(ws);              // 8388608 B each
    uint16_t* qlo  = (uint16_t*)(ws + 8388608);
    uint16_t* khi  = (uint16_t*)(ws + 16777216);
    uint16_t* klo  = (uint16_t*)(ws + 25165824);
    uint16_t* vT   = (uint16_t*)(ws + 33554432);   // [B*H][64][2048] bf16
    uint16_t* xhi  = (uint16_t*)(ws + 41943040);   // 8388608 B
    uint16_t* xlo  = (uint16_t*)(ws + 50331648);   // 8388608 B
    uint16_t* whiT = (uint16_t*)(ws + 58720256);   // 1572864 B
    uint16_t* wloT = (uint16_t*)(ws + 60293120);
    uint16_t* woT  = (uint16_t*)(ws + 61865984);   // 65536 B
    // oc aliases xhi (dead after gemm_qkv; split_x rewrites it every call).
    uint16_t* oc   = xhi;

    hipLaunchKernelGGL(prep_w, dim3(200), dim3(256), 0, stream, w, wo, whiT, wloT, woT);
    hipLaunchKernelGGL(split_x, dim3(2048), dim3(256), 0, stream, x, xhi, xlo);
    hipLaunchKernelGGL(gemm_qkv, dim3(768), dim3(256), 0, stream,
                       xhi, xlo, whiT, wloT, qhi, qlo, khi, klo, vT);
    hipLaunchKernelGGL(attn_fwd, dim3(512), dim3(256), 0, stream,
                       qhi, qlo, khi, klo, vT, oc);
    hipLaunchKernelGGL(oproj, dim3(128), dim3(256), 0, stream, oc, woT, out);
}

// Round 10
// 131.876 us; speedup vs baseline: 1.2226x; 1.2183x over previous
//
#include <hip/hip_runtime.h>
#include <cstdint>
#include <cstddef>

#define S_LEN 2048
#define DIN   512
#define DOUT  64
#define NB    4
#define NH    8

typedef __attribute__((ext_vector_type(8))) short bf16x8;
typedef __attribute__((ext_vector_type(8))) _Float16 f16x8;
typedef __attribute__((ext_vector_type(4))) float f32x4;
typedef __attribute__((ext_vector_type(16))) float f32x16;

static __device__ __forceinline__ f32x4 mfma16(bf16x8 a, bf16x8 b, f32x4 c) {
    return __builtin_amdgcn_mfma_f32_16x16x32_bf16(a, b, c, 0, 0, 0);
}
static __device__ __forceinline__ f32x16 mfma32h(f16x8 a, f16x8 b, f32x16 c) {
    return __builtin_amdgcn_mfma_f32_32x32x16_f16(a, b, c, 0, 0, 0);
}

static __device__ __forceinline__ uint16_t f2bf(float x) {
    uint32_t u = __builtin_bit_cast(uint32_t, x);
    u += 0x7fffu + ((u >> 16) & 1u);
    return (uint16_t)(u >> 16);
}
static __device__ __forceinline__ float bf2f(uint16_t h) {
    uint32_t u = ((uint32_t)h) << 16;
    return __builtin_bit_cast(float, u);
}
static __device__ __forceinline__ uint32_t cvt_pk_bf16(float lo, float hi) {
    uint32_t r;
    asm("v_cvt_pk_bf16_f32 %0, %1, %2" : "=v"(r) : "v"(lo), "v"(hi));
    return r;
}
static __device__ __forceinline__ uint32_t cvt_pkrtz_f16(float lo, float hi) {
    return __builtin_bit_cast(uint32_t, __builtin_amdgcn_cvt_pkrtz(lo, hi));
}

typedef const __attribute__((address_space(1))) void* as1p;
typedef __attribute__((address_space(3))) void* as3p;
static __device__ __forceinline__ void gload_lds16(const void* g, void* l) {
    __builtin_amdgcn_global_load_lds((as1p)g, (as3p)l, 16, 0, 0);
}

// ---------------------------------------------------------------------------
// Kernel 1: weight prep via LDS transpose (coalesced both sides).
// ---------------------------------------------------------------------------
__global__ __launch_bounds__(256) void prep_w(
    const float* __restrict__ w, const float* __restrict__ wo,
    uint16_t* __restrict__ whiT, uint16_t* __restrict__ wloT,
    uint16_t* __restrict__ woT)
{
    __shared__ float tile[64][65];
    const int blk = blockIdx.x;
    const int t = threadIdx.x;
    const int tq = t >> 6, tr = t & 63;

    if (blk < 192) {
        const int hp = blk >> 3, i0 = (blk & 7) * 64;
        const int p = hp % 3;
        const float s = (p == 0) ? 0.18033688011112042f : 1.0f; // 0.125*log2(e)
        const float* __restrict__ src = w + (size_t)hp * (DIN * DOUT);
        #pragma unroll
        for (int r = 0; r < 16; ++r) {
            const int ir = r * 4 + tq;
            tile[ir][tr] = src[(size_t)(i0 + ir) * DOUT + tr];
        }
        __syncthreads();
        uint16_t* __restrict__ dh = whiT + (size_t)hp * (DOUT * DIN);
        uint16_t* __restrict__ dl = wloT + (size_t)hp * (DOUT * DIN);
        #pragma unroll
        for (int r = 0; r < 16; ++r) {
            const int o = r * 4 + tq;
            const float v = tile[tr][o] * s;
            const uint16_t hi = f2bf(v);
            dh[(size_t)o * DIN + i0 + tr] = hi;
            dl[(size_t)o * DIN + i0 + tr] = f2bf(v - bf2f(hi));
        }
    } else {
        const int i0 = (blk - 192) * 64;
        #pragma unroll
        for (int r = 0; r < 16; ++r) {
            const int ir = r * 4 + tq;
            tile[ir][tr] = wo[(size_t)(i0 + ir) * DOUT + tr];
        }
        __syncthreads();
        #pragma unroll
        for (int r = 0; r < 16; ++r) {
            const int o = r * 4 + tq;
            woT[(size_t)o * DIN + i0 + tr] = f2bf(tile[tr][o]);
        }
    }
}

// ---------------------------------------------------------------------------
// Kernel 2: split x [8192][512] fp32 -> xhi/xlo bf16 (vectorized, one pass).
// ---------------------------------------------------------------------------
__global__ __launch_bounds__(256) void split_x(
    const float* __restrict__ x, uint16_t* __restrict__ xhi, uint16_t* __restrict__ xlo)
{
    const size_t idx = ((size_t)blockIdx.x * 256 + threadIdx.x) * 8;
    const float4 a = *(const float4*)(x + idx);
    const float4 b = *(const float4*)(x + idx + 4);
    const float xv[8] = {a.x, a.y, a.z, a.w, b.x, b.y, b.z, b.w};
    union { uint16_t u[8]; uint4 v; } H, L;
    #pragma unroll
    for (int j = 0; j < 8; ++j) {
        const uint16_t hi = f2bf(xv[j]);
        H.u[j] = hi;
        L.u[j] = f2bf(xv[j] - bf2f(hi));
    }
    *(uint4*)(xhi + idx) = H.v;
    *(uint4*)(xlo + idx) = L.v;
}

// ---------------------------------------------------------------------------
// Kernel 3: QKV projection GEMM (m97 structure, bf16x3 internally).
// Outputs: q,k fp16 [bh][s][64]; vT fp16 [bh][d][s] (pre-transposed).
// ---------------------------------------------------------------------------
__global__ __launch_bounds__(256) void gemm_qkv(
    const uint16_t* __restrict__ xhi, const uint16_t* __restrict__ xlo,
    const uint16_t* __restrict__ whiT, const uint16_t* __restrict__ wloT,
    uint16_t* __restrict__ qf, uint16_t* __restrict__ kf,
    uint16_t* __restrict__ vT)
{
    __shared__ __align__(16) uint16_t lds[2 * 128 * 64];

    const int bid = blockIdx.x;
    const int xcd = bid & 7, wi = bid >> 3;
    const int mt = xcd * 8 + wi / 12, nt = wi % 12;
    const int m0 = mt * 128, n0 = nt * 128;
    const int tid = threadIdx.x;
    const int l = tid & 63, w = tid >> 6;
    const int g = l >> 4, lm = l & 15;
    const int wm = w >> 1, wn = w & 1;

    const f32x4 Z = {0.f, 0.f, 0.f, 0.f};
    f32x4 acc[4][4];
    #pragma unroll
    for (int a = 0; a < 4; ++a)
        #pragma unroll
        for (int b = 0; b < 4; ++b) acc[a][b] = Z;

    int srow[4], scol[4];
    #pragma unroll
    for (int i = 0; i < 4; ++i) {
        const int c = i * 256 + tid;
        srow[i] = c >> 3;
        scol[i] = ((c & 7) * 8) ^ ((srow[i] & 7) << 3);
    }

    for (int kt = 0; kt < 24; ++kt) {
        const int k0 = (kt & 7) * 64;
        const uint16_t* __restrict__ As = (kt < 16) ? xhi : xlo;
        const uint16_t* __restrict__ Bs = (kt >= 8 && kt < 16) ? wloT : whiT;
        #pragma unroll
        for (int i = 0; i < 4; ++i) {
            const int c8 = (i * 256 + tid) * 8;
            gload_lds16(As + (size_t)(m0 + srow[i]) * DIN + k0 + scol[i], &lds[c8]);
            gload_lds16(Bs + (size_t)(n0 + srow[i]) * DIN + k0 + scol[i], &lds[128 * 64 + c8]);
        }
        asm volatile("s_waitcnt vmcnt(0)" ::: "memory");
        __syncthreads();

        bf16x8 af[4][2];
        #pragma unroll
        for (int mi = 0; mi < 4; ++mi) {
            const int r = wm * 64 + mi * 16 + lm;
            const int rb = r * 128;
            #pragma unroll
            for (int kk = 0; kk < 2; ++kk) {
                const int cb = (kk * 64 + g * 16) ^ ((r & 7) << 4);
                af[mi][kk] = *(const bf16x8*)((const char*)lds + rb + cb);
            }
        }
        #pragma unroll
        for (int ni = 0; ni < 4; ++ni) {
            const int r = wn * 64 + ni * 16 + lm;
            const int rb = 128 * 64 * 2 + r * 128;
            bf16x8 bfr[2];
            #pragma unroll
            for (int kk = 0; kk < 2; ++kk) {
                const int cb = (kk * 64 + g * 16) ^ ((r & 7) << 4);
                bfr[kk] = *(const bf16x8*)((const char*)lds + rb + cb);
            }
            #pragma unroll
            for (int mi = 0; mi < 4; ++mi) {
                acc[mi][ni] = mfma16(af[mi][0], bfr[0], acc[mi][ni]);
                acc[mi][ni] = mfma16(af[mi][1], bfr[1], acc[mi][ni]);
            }
        }
        __syncthreads();
    }

    #pragma unroll
    for (int ni = 0; ni < 4; ++ni) {
        const int n = n0 + wn * 64 + ni * 16 + lm;
        const int hp = n >> 6, o = n & 63;
        const int h = hp / 3, p = hp - h * 3;
        if (p < 2) {
            uint16_t* __restrict__ dst = (p == 0) ? qf : kf;
            #pragma unroll
            for (int mi = 0; mi < 4; ++mi) {
                #pragma unroll
                for (int j = 0; j < 4; ++j) {
                    const int m = m0 + wm * 64 + mi * 16 + 4 * g + j;
                    const int b = m >> 11, s = m & 2047;
                    const size_t idx = ((size_t)(b * NH + h) * S_LEN + s) * DOUT + o;
                    const _Float16 hv = (_Float16)acc[mi][ni][j];  // RNE
                    dst[idx] = __builtin_bit_cast(uint16_t, hv);
                }
            }
        } else {
            #pragma unroll
            for (int mi = 0; mi < 4; ++mi) {
                const int m = m0 + wm * 64 + mi * 16 + 4 * g;  // 4 consecutive s
                const int b = m >> 11, s = m & 2047;
                union { _Float16 h[4]; uint2 u; } pk;
                pk.h[0] = (_Float16)acc[mi][ni][0];
                pk.h[1] = (_Float16)acc[mi][ni][1];
                pk.h[2] = (_Float16)acc[mi][ni][2];
                pk.h[3] = (_Float16)acc[mi][ni][3];
                *(uint2*)(vT + ((size_t)((b * NH + h) * DOUT + o)) * S_LEN + s) = pk.u;
            }
        }
    }
}

// ---------------------------------------------------------------------------
// Kernel 4: flash attention, fp16 32x32 MFMA, in-register softmax, fragment-
//   major LDS (zero bank conflicts), R8 pipeline (QK(kt+1) MFMA || softmax(kt)
//   VALU; one vmcnt(0)+barrier per iter). Tree max/sum; cross-half scalar
//   reductions via __shfl_xor (NOT permlane-on-equal-values: regalloc may
//   coalesce the two operands into one register -> swap degenerates, R9 NaN).
//   LDS 32KB: kbuf0/1 (8KB fp16 each) + vbuf0/1 (8KB each).
// ---------------------------------------------------------------------------
__global__ __launch_bounds__(256, 2) void attn_fwd(
    const uint16_t* __restrict__ qf, const uint16_t* __restrict__ kf,
    const uint16_t* __restrict__ vT, uint16_t* __restrict__ oc)
{
    __shared__ __align__(16) char smem[32768];
    // kbuf0 @0, kbuf1 @8192, vbuf0 @16384, vbuf1 @24576
    char* __restrict__ vbufs = smem + 16384;

    const int bid = blockIdx.x;
    const int qt = (bid >> 3) & 15, bh = (bid & 7) + 8 * (bid >> 7);
    const int tid = threadIdx.x;
    const int l = tid & 63, wq = tid >> 6;
    const int L = l >> 5, lq = l & 31;
    const size_t base = (size_t)bh * (S_LEN * DOUT);

    // fragment-major staging: chunk c -> LDS byte c*16; source granule:
    //   row  = ((c>>8)<<5) | (c&31), doff = ((c>>5)&7) << 3
    const int c0 = tid, c1 = tid + 256;
    const int kr0 = c0 & 31,        do0 = ((c0 >> 5) & 7) << 3;
    const int kr1 = 32 + (c1 & 31), do1 = ((c1 >> 5) & 7) << 3;

    // Q B-fragments (fp16): lane holds Q[q = qrow][d = dsub*16 + 8L + j]
    const int qrow = qt * 128 + wq * 32 + lq;
    const uint16_t* qp = qf + base + (size_t)qrow * DOUT;
    f16x8 qv[4];
    #pragma unroll
    for (int dsub = 0; dsub < 4; ++dsub)
        qv[dsub] = *(const f16x8*)(qp + dsub * 16 + L * 8);

    f32x16 Zv;
    #pragma unroll
    for (int r = 0; r < 16; ++r) Zv[r] = 0.f;
    f32x16 Oa[2] = {Zv, Zv};           // O^T[d = dh*32 + row(reg,L)][q = lq]
    float m_run = -INFINITY, l_run = 0.f;

    auto qk_step = [&](const char* kb2, f32x16* dst) {
        #pragma unroll
        for (int ks = 0; ks < 2; ++ks) {
            f32x16 s = Zv;
            #pragma unroll
            for (int dsub = 0; dsub < 4; ++dsub) {
                const uint32_t off = (uint32_t)(((ks * 4 + dsub) << 10) + (l << 4));
                const f16x8 kfr = *(const f16x8*)(kb2 + off);
                s = mfma32h(kfr, qv[dsub], s);
            }
            dst[ks] = s;
        }
    };

    // prologue: K(0)->kbuf0, K(1)->kbuf1, V(0)->vbuf0
    gload_lds16(kf + base + (size_t)kr0 * DOUT + do0, smem + c0 * 16);
    gload_lds16(kf + base + (size_t)kr1 * DOUT + do1, smem + c1 * 16);
    gload_lds16(kf + base + (size_t)(64 + kr0) * DOUT + do0, smem + 8192 + c0 * 16);
    gload_lds16(kf + base + (size_t)(64 + kr1) * DOUT + do1, smem + 8192 + c1 * 16);
    gload_lds16(vT + base + (size_t)kr0 * S_LEN + do0, vbufs + c0 * 16);
    gload_lds16(vT + base + (size_t)kr1 * S_LEN + do1, vbufs + c1 * 16);
    asm volatile("s_waitcnt vmcnt(0)" ::: "memory");
    __builtin_amdgcn_s_barrier();
    __builtin_amdgcn_sched_barrier(0);

    f32x16 saA[2], saB[2];
    qk_step(smem, saA);                // QK(0) from kbuf0

    auto iter = [&](int kt, f32x16* sa, f32x16* sb) {
        // [a] everything issued last iter (K(kt+1), V(kt)) resident
        asm volatile("s_waitcnt vmcnt(0)" ::: "memory");
        __builtin_amdgcn_s_barrier();
        __builtin_amdgcn_sched_barrier(0);

        // [b] DMA: K(kt+2) -> kbuf[kt&1], V(kt+1) -> vbuf[(kt+1)&1]
        {
            char* __restrict__ kn = smem + (kt & 1) * 8192;
            const int sK = (kt < 30) ? (kt + 2) * 64 : 0;
            gload_lds16(kf + base + (size_t)(sK + kr0) * DOUT + do0, kn + c0 * 16);
            gload_lds16(kf + base + (size_t)(sK + kr1) * DOUT + do1, kn + c1 * 16);
            char* __restrict__ vn = vbufs + ((kt + 1) & 1) * 8192;
            const int sV = (kt < 31) ? (kt + 1) * 64 : 0;
            gload_lds16(vT + base + (size_t)kr0 * S_LEN + sV + do0, vn + c0 * 16);
            gload_lds16(vT + base + (size_t)kr1 * S_LEN + sV + do1, vn + c1 * 16);
        }

        // [c] QK(kt+1) -> sb (MFMA)  ||  softmax(kt) on sa (VALU/TRANS)
        qk_step(smem + ((kt + 1) & 1) * 8192, sb);

        // tree max (depth 5, ILP 16)
        float mx[16];
        #pragma unroll
        for (int r = 0; r < 16; ++r) mx[r] = fmaxf(sa[0][r], sa[1][r]);
        #pragma unroll
        for (int st = 8; st >= 1; st >>= 1)
            #pragma unroll
            for (int r = 0; r < st; ++r) mx[r] = fmaxf(mx[r], mx[r + st]);
        float pmax = mx[0];
        pmax = fmaxf(pmax, __shfl_xor(pmax, 32));

        if (!__all(pmax - m_run <= 8.f)) {
            const float m_new = fmaxf(m_run, pmax);
            const float alpha = __builtin_amdgcn_exp2f(m_run - m_new);
            m_run = m_new;
            #pragma unroll
            for (int r = 0; r < 16; ++r) { Oa[0][r] *= alpha; Oa[1][r] *= alpha; }
            l_run *= alpha;
        }

        #pragma unroll
        for (int ks = 0; ks < 2; ++ks)
            #pragma unroll
            for (int r = 0; r < 16; ++r)
                sa[ks][r] = __builtin_amdgcn_exp2f(sa[ks][r] - m_run);

        // tree sum (depth 5)
        float sm[16];
        #pragma unroll
        for (int r = 0; r < 16; ++r) sm[r] = sa[0][r] + sa[1][r];
        #pragma unroll
        for (int st = 8; st >= 1; st >>= 1)
            #pragma unroll
            for (int r = 0; r < st; ++r) sm[r] += sm[r + st];
        float lsum = sm[0];
        lsum += __shfl_xor(lsum, 32);
        l_run += lsum;

        // pack P (fp16, pkrtz) into PV B-fragments; permlane VDST = lo pack
        f16x8 pfrag[4];
        #pragma unroll
        for (int ks = 0; ks < 2; ++ks) {
            uint32_t a0 = cvt_pkrtz_f16(sa[ks][0], sa[ks][1]);
            uint32_t a1 = cvt_pkrtz_f16(sa[ks][2], sa[ks][3]);
            uint32_t a2 = cvt_pkrtz_f16(sa[ks][4], sa[ks][5]);
            uint32_t a3 = cvt_pkrtz_f16(sa[ks][6], sa[ks][7]);
            asm volatile("v_permlane32_swap_b32 %0, %1" : "+v"(a0), "+v"(a2));
            asm volatile("v_permlane32_swap_b32 %0, %1" : "+v"(a1), "+v"(a3));
            union { uint32_t w[4]; f16x8 v; } u;
            u.w[0] = a0; u.w[1] = a1; u.w[2] = a2; u.w[3] = a3;
            pfrag[2 * ks] = u.v;
            uint32_t b0 = cvt_pkrtz_f16(sa[ks][8],  sa[ks][9]);
            uint32_t b1 = cvt_pkrtz_f16(sa[ks][10], sa[ks][11]);
            uint32_t b2 = cvt_pkrtz_f16(sa[ks][12], sa[ks][13]);
            uint32_t b3 = cvt_pkrtz_f16(sa[ks][14], sa[ks][15]);
            asm volatile("v_permlane32_swap_b32 %0, %1" : "+v"(b0), "+v"(b2));
            asm volatile("v_permlane32_swap_b32 %0, %1" : "+v"(b1), "+v"(b3));
            union { uint32_t w[4]; f16x8 v; } u2;
            u2.w[0] = b0; u2.w[1] = b1; u2.w[2] = b2; u2.w[3] = b3;
            pfrag[2 * ks + 1] = u2.v;
        }

        // [d] PV(kt) from vbuf[kt&1] (fragment-major, conflict-free)
        const char* __restrict__ vb = vbufs + (kt & 1) * 8192;
        __builtin_amdgcn_s_setprio(1);
        #pragma unroll
        for (int dh = 0; dh < 2; ++dh) {
            #pragma unroll
            for (int kc = 0; kc < 4; ++kc) {
                const uint32_t off = (uint32_t)(((dh * 4 + kc) << 10) + (l << 4));
                const f16x8 vv = *(const f16x8*)(vb + off);
                Oa[dh] = mfma32h(vv, pfrag[kc], Oa[dh]);
            }
        }
        __builtin_amdgcn_s_setprio(0);
    };

    for (int kt2 = 0; kt2 < 16; ++kt2) {
        iter(2 * kt2,     saA, saB);
        iter(2 * kt2 + 1, saB, saA);
    }
    asm volatile("s_waitcnt vmcnt(0)" ::: "memory");

    // epilogue: lane-local normalize; O^T -> oc[b][s][h*64+d] bf16, 8B packed
    const int b = bh >> 3, hh = bh & 7;
    const float li = 1.f / l_run;
    const int srow = qt * 128 + wq * 32 + lq;
    const size_t rbase = ((size_t)b * S_LEN + srow) * (NH * DOUT) + hh * DOUT;
    #pragma unroll
    for (int dh = 0; dh < 2; ++dh) {
        #pragma unroll
        for (int rq = 0; rq < 4; ++rq) {
            const int d0 = dh * 32 + rq * 8 + L * 4;
            uint2 val;
            val.x = cvt_pk_bf16(Oa[dh][rq * 4 + 0] * li, Oa[dh][rq * 4 + 1] * li);
            val.y = cvt_pk_bf16(Oa[dh][rq * 4 + 2] * li, Oa[dh][rq * 4 + 3] * li);
            *(uint2*)(oc + rbase + d0) = val;
        }
    }
}

// ---------------------------------------------------------------------------
// Kernel 5: output projection out = o_concat[8192x512] @ wo[512x64], fp32 out.
// ---------------------------------------------------------------------------
__global__ __launch_bounds__(256) void oproj(
    const uint16_t* __restrict__ oc, const uint16_t* __restrict__ woT,
    float* __restrict__ out)
{
    const int mt = blockIdx.x;
    const int tid = threadIdx.x;
    const int l = tid & 63, w = tid >> 6;
    const int g = l >> 4, lm = l & 15;
    const int m0 = mt * 64 + w * 16;
    const f32x4 Z = {0.f, 0.f, 0.f, 0.f};
    f32x4 acc[4] = {Z, Z, Z, Z};
    const uint16_t* __restrict__ arow = oc + (size_t)(m0 + lm) * (NH * DOUT);
    for (int kc = 0; kc < 16; ++kc) {
        const bf16x8 a = *(const bf16x8*)(arow + kc * 32 + g * 8);
        #pragma unroll
        for (int nt = 0; nt < 4; ++nt) {
            const bf16x8 bfr = *(const bf16x8*)(woT + (size_t)(nt * 16 + lm) * (NH * DOUT) + kc * 32 + g * 8);
            acc[nt] = mfma16(a, bfr, acc[nt]);
        }
    }
    #pragma unroll
    for (int nt = 0; nt < 4; ++nt)
        #pragma unroll
        for (int j = 0; j < 4; ++j)
            out[(size_t)(m0 + 4 * g + j) * DOUT + nt * 16 + lm] = acc[nt][j];
}

// ---------------------------------------------------------------------------
extern "C" void kernel_launch(void* const* d_in, const int* in_sizes, int n_in,
                              void* d_out, int out_size, void* d_ws, size_t ws_size,
                              hipStream_t stream) {
    const float* x  = (const float*)d_in[0];
    const float* w  = (const float*)d_in[1];
    const float* wo = (const float*)d_in[2];
    float* out = (float*)d_out;

    char* ws = (char*)d_ws;
    uint16_t* qf   = (uint16_t*)(ws);              // [B*H][S][64] fp16, 8 MB
    uint16_t* kf   = (uint16_t*)(ws + 8388608);    // fp16, 8 MB
    uint16_t* vT   = (uint16_t*)(ws + 16777216);   // [B*H][64][S] fp16, 8 MB
    uint16_t* xhi  = (uint16_t*)(ws + 25165824);   // bf16, 8 MB
    uint16_t* xlo  = (uint16_t*)(ws + 33554432);   // bf16, 8 MB
    uint16_t* whiT = (uint16_t*)(ws + 41943040);   // [1536][512] bf16
    uint16_t* wloT = (uint16_t*)(ws + 43515904);
    uint16_t* woT  = (uint16_t*)(ws + 45088768);   // 65536 B
    // oc aliases xhi (dead after gemm_qkv; split_x rewrites it every call).
    uint16_t* oc   = xhi;
    // total: 45154304 B (~43 MB)

    hipLaunchKernelGGL(prep_w, dim3(200), dim3(256), 0, stream, w, wo, whiT, wloT, woT);
    hipLaunchKernelGGL(split_x, dim3(2048), dim3(256), 0, stream, x, xhi, xlo);
    hipLaunchKernelGGL(gemm_qkv, dim3(768), dim3(256), 0, stream,
                       xhi, xlo, whiT, wloT, qf, kf, vT);
    hipLaunchKernelGGL(attn_fwd, dim3(512), dim3(256), 0, stream,
                       qf, kf, vT, oc);
    hipLaunchKernelGGL(oproj, dim3(128), dim3(256), 0, stream, oc, woT, out);
}

// Round 11
// 114.301 us; speedup vs baseline: 1.4105x; 1.1538x over previous
//
#include <hip/hip_runtime.h>
#include <cstdint>
#include <cstddef>

#define S_LEN 2048
#define DIN   512
#define DOUT  64
#define NB    4
#define NH    8

typedef __attribute__((ext_vector_type(8))) short bf16x8;
typedef __attribute__((ext_vector_type(8))) _Float16 f16x8;
typedef __attribute__((ext_vector_type(4))) float f32x4;
typedef __attribute__((ext_vector_type(16))) float f32x16;

static __device__ __forceinline__ f32x4 mfma16(bf16x8 a, bf16x8 b, f32x4 c) {
    return __builtin_amdgcn_mfma_f32_16x16x32_bf16(a, b, c, 0, 0, 0);
}
static __device__ __forceinline__ f32x16 mfma32h(f16x8 a, f16x8 b, f32x16 c) {
    return __builtin_amdgcn_mfma_f32_32x32x16_f16(a, b, c, 0, 0, 0);
}

static __device__ __forceinline__ uint16_t f2bf(float x) {
    uint32_t u = __builtin_bit_cast(uint32_t, x);
    u += 0x7fffu + ((u >> 16) & 1u);
    return (uint16_t)(u >> 16);
}
static __device__ __forceinline__ float bf2f(uint16_t h) {
    uint32_t u = ((uint32_t)h) << 16;
    return __builtin_bit_cast(float, u);
}
static __device__ __forceinline__ uint32_t cvt_pk_bf16(float lo, float hi) {
    uint32_t r;
    asm("v_cvt_pk_bf16_f32 %0, %1, %2" : "=v"(r) : "v"(lo), "v"(hi));
    return r;
}
static __device__ __forceinline__ uint32_t cvt_pkrtz_f16(float lo, float hi) {
    return __builtin_bit_cast(uint32_t, __builtin_amdgcn_cvt_pkrtz(lo, hi));
}

typedef const __attribute__((address_space(1))) void* as1p;
typedef __attribute__((address_space(3))) void* as3p;
static __device__ __forceinline__ void gload_lds16(const void* g, void* l) {
    __builtin_amdgcn_global_load_lds((as1p)g, (as3p)l, 16, 0, 0);
}

// ---------------------------------------------------------------------------
// Kernel 1: weight prep via LDS transpose (coalesced both sides).
// ---------------------------------------------------------------------------
__global__ __launch_bounds__(256) void prep_w(
    const float* __restrict__ w, const float* __restrict__ wo,
    uint16_t* __restrict__ whiT, uint16_t* __restrict__ wloT,
    uint16_t* __restrict__ woT)
{
    __shared__ float tile[64][65];
    const int blk = blockIdx.x;
    const int t = threadIdx.x;
    const int tq = t >> 6, tr = t & 63;

    if (blk < 192) {
        const int hp = blk >> 3, i0 = (blk & 7) * 64;
        const int p = hp % 3;
        const float s = (p == 0) ? 0.18033688011112042f : 1.0f; // 0.125*log2(e)
        const float* __restrict__ src = w + (size_t)hp * (DIN * DOUT);
        #pragma unroll
        for (int r = 0; r < 16; ++r) {
            const int ir = r * 4 + tq;
            tile[ir][tr] = src[(size_t)(i0 + ir) * DOUT + tr];
        }
        __syncthreads();
        uint16_t* __restrict__ dh = whiT + (size_t)hp * (DOUT * DIN);
        uint16_t* __restrict__ dl = wloT + (size_t)hp * (DOUT * DIN);
        #pragma unroll
        for (int r = 0; r < 16; ++r) {
            const int o = r * 4 + tq;
            const float v = tile[tr][o] * s;
            const uint16_t hi = f2bf(v);
            dh[(size_t)o * DIN + i0 + tr] = hi;
            dl[(size_t)o * DIN + i0 + tr] = f2bf(v - bf2f(hi));
        }
    } else {
        const int i0 = (blk - 192) * 64;
        #pragma unroll
        for (int r = 0; r < 16; ++r) {
            const int ir = r * 4 + tq;
            tile[ir][tr] = wo[(size_t)(i0 + ir) * DOUT + tr];
        }
        __syncthreads();
        #pragma unroll
        for (int r = 0; r < 16; ++r) {
            const int o = r * 4 + tq;
            woT[(size_t)o * DIN + i0 + tr] = f2bf(tile[tr][o]);
        }
    }
}

// ---------------------------------------------------------------------------
// Kernel 2: split x [8192][512] fp32 -> xhi/xlo bf16 (vectorized, one pass).
// ---------------------------------------------------------------------------
__global__ __launch_bounds__(256) void split_x(
    const float* __restrict__ x, uint16_t* __restrict__ xhi, uint16_t* __restrict__ xlo)
{
    const size_t idx = ((size_t)blockIdx.x * 256 + threadIdx.x) * 8;
    const float4 a = *(const float4*)(x + idx);
    const float4 b = *(const float4*)(x + idx + 4);
    const float xv[8] = {a.x, a.y, a.z, a.w, b.x, b.y, b.z, b.w};
    union { uint16_t u[8]; uint4 v; } H, L;
    #pragma unroll
    for (int j = 0; j < 8; ++j) {
        const uint16_t hi = f2bf(xv[j]);
        H.u[j] = hi;
        L.u[j] = f2bf(xv[j] - bf2f(hi));
    }
    *(uint4*)(xhi + idx) = H.v;
    *(uint4*)(xlo + idx) = L.v;
}

// ---------------------------------------------------------------------------
// Kernel 3: QKV projection GEMM, FUSED 3-term split precision:
//   acc = xhi*whi + xhi*wlo + xlo*whi computed per K-step with shared tiles.
//   8 K-steps of BK=64; 4 tiles (xhi,xlo,whi,wlo) staged per step (64KB LDS);
//   fragments register-reused (ah used x2, bh used x2) -> 96 MFMA per
//   barrier-pair (3x the R10 ratio), tile-stages 48->32, barriers 48->16.
// Outputs: q,k fp16 [bh][s][64]; vT fp16 [bh][d][s] (pre-transposed).
// ---------------------------------------------------------------------------
__global__ __launch_bounds__(256, 2) void gemm_qkv(
    const uint16_t* __restrict__ xhi, const uint16_t* __restrict__ xlo,
    const uint16_t* __restrict__ whiT, const uint16_t* __restrict__ wloT,
    uint16_t* __restrict__ qf, uint16_t* __restrict__ kf,
    uint16_t* __restrict__ vT)
{
    __shared__ __align__(16) uint16_t lds[4 * 128 * 64];   // 64 KB: ah|al|bh|bl

    const int bid = blockIdx.x;
    const int xcd = bid & 7, wi = bid >> 3;
    const int mt = xcd * 8 + wi / 12, nt = wi % 12;
    const int m0 = mt * 128, n0 = nt * 128;
    const int tid = threadIdx.x;
    const int l = tid & 63, w = tid >> 6;
    const int g = l >> 4, lm = l & 15;
    const int wm = w >> 1, wn = w & 1;

    const f32x4 Z = {0.f, 0.f, 0.f, 0.f};
    f32x4 acc[4][4];
    #pragma unroll
    for (int a = 0; a < 4; ++a)
        #pragma unroll
        for (int b = 0; b < 4; ++b) acc[a][b] = Z;

    int srow[4], scol[4];
    #pragma unroll
    for (int i = 0; i < 4; ++i) {
        const int c = i * 256 + tid;
        srow[i] = c >> 3;
        scol[i] = ((c & 7) * 8) ^ ((srow[i] & 7) << 3);
    }

    for (int kt = 0; kt < 8; ++kt) {
        const int k0 = kt * 64;
        #pragma unroll
        for (int i = 0; i < 4; ++i) {
            const int c8 = (i * 256 + tid) * 8;
            const size_t aoff = (size_t)(m0 + srow[i]) * DIN + k0 + scol[i];
            const size_t boff = (size_t)(n0 + srow[i]) * DIN + k0 + scol[i];
            gload_lds16(xhi  + aoff, &lds[c8]);
            gload_lds16(xlo  + aoff, &lds[128 * 64 + c8]);
            gload_lds16(whiT + boff, &lds[2 * 128 * 64 + c8]);
            gload_lds16(wloT + boff, &lds[3 * 128 * 64 + c8]);
        }
        asm volatile("s_waitcnt vmcnt(0)" ::: "memory");
        __syncthreads();

        bf16x8 ah[4][2], al[4][2];
        #pragma unroll
        for (int mi = 0; mi < 4; ++mi) {
            const int r = wm * 64 + mi * 16 + lm;
            const int rb = r * 128;
            #pragma unroll
            for (int kk = 0; kk < 2; ++kk) {
                const int cb = (kk * 64 + g * 16) ^ ((r & 7) << 4);
                ah[mi][kk] = *(const bf16x8*)((const char*)lds + rb + cb);
                al[mi][kk] = *(const bf16x8*)((const char*)lds + 16384 + rb + cb);
            }
        }
        #pragma unroll
        for (int ni = 0; ni < 4; ++ni) {
            const int r = wn * 64 + ni * 16 + lm;
            const int rb = r * 128;
            bf16x8 bh[2], bl[2];
            #pragma unroll
            for (int kk = 0; kk < 2; ++kk) {
                const int cb = (kk * 64 + g * 16) ^ ((r & 7) << 4);
                bh[kk] = *(const bf16x8*)((const char*)lds + 32768 + rb + cb);
                bl[kk] = *(const bf16x8*)((const char*)lds + 49152 + rb + cb);
            }
            #pragma unroll
            for (int mi = 0; mi < 4; ++mi) {
                acc[mi][ni] = mfma16(ah[mi][0], bh[0], acc[mi][ni]);
                acc[mi][ni] = mfma16(ah[mi][1], bh[1], acc[mi][ni]);
                acc[mi][ni] = mfma16(ah[mi][0], bl[0], acc[mi][ni]);
                acc[mi][ni] = mfma16(ah[mi][1], bl[1], acc[mi][ni]);
                acc[mi][ni] = mfma16(al[mi][0], bh[0], acc[mi][ni]);
                acc[mi][ni] = mfma16(al[mi][1], bh[1], acc[mi][ni]);
            }
        }
        __syncthreads();
    }

    #pragma unroll
    for (int ni = 0; ni < 4; ++ni) {
        const int n = n0 + wn * 64 + ni * 16 + lm;
        const int hp = n >> 6, o = n & 63;
        const int h = hp / 3, p = hp - h * 3;
        if (p < 2) {
            uint16_t* __restrict__ dst = (p == 0) ? qf : kf;
            #pragma unroll
            for (int mi = 0; mi < 4; ++mi) {
                #pragma unroll
                for (int j = 0; j < 4; ++j) {
                    const int m = m0 + wm * 64 + mi * 16 + 4 * g + j;
                    const int b = m >> 11, s = m & 2047;
                    const size_t idx = ((size_t)(b * NH + h) * S_LEN + s) * DOUT + o;
                    const _Float16 hv = (_Float16)acc[mi][ni][j];  // RNE
                    dst[idx] = __builtin_bit_cast(uint16_t, hv);
                }
            }
        } else {
            #pragma unroll
            for (int mi = 0; mi < 4; ++mi) {
                const int m = m0 + wm * 64 + mi * 16 + 4 * g;  // 4 consecutive s
                const int b = m >> 11, s = m & 2047;
                union { _Float16 h[4]; uint2 u; } pk;
                pk.h[0] = (_Float16)acc[mi][ni][0];
                pk.h[1] = (_Float16)acc[mi][ni][1];
                pk.h[2] = (_Float16)acc[mi][ni][2];
                pk.h[3] = (_Float16)acc[mi][ni][3];
                *(uint2*)(vT + ((size_t)((b * NH + h) * DOUT + o)) * S_LEN + s) = pk.u;
            }
        }
    }
}

// ---------------------------------------------------------------------------
// Kernel 4: flash attention (unchanged from passing R10): fp16 32x32 MFMA,
//   in-register softmax, fragment-major LDS, QK(kt+1)||softmax(kt) pipeline.
// ---------------------------------------------------------------------------
__global__ __launch_bounds__(256, 2) void attn_fwd(
    const uint16_t* __restrict__ qf, const uint16_t* __restrict__ kf,
    const uint16_t* __restrict__ vT, uint16_t* __restrict__ oc)
{
    __shared__ __align__(16) char smem[32768];
    // kbuf0 @0, kbuf1 @8192, vbuf0 @16384, vbuf1 @24576
    char* __restrict__ vbufs = smem + 16384;

    const int bid = blockIdx.x;
    const int qt = (bid >> 3) & 15, bh = (bid & 7) + 8 * (bid >> 7);
    const int tid = threadIdx.x;
    const int l = tid & 63, wq = tid >> 6;
    const int L = l >> 5, lq = l & 31;
    const size_t base = (size_t)bh * (S_LEN * DOUT);

    const int c0 = tid, c1 = tid + 256;
    const int kr0 = c0 & 31,        do0 = ((c0 >> 5) & 7) << 3;
    const int kr1 = 32 + (c1 & 31), do1 = ((c1 >> 5) & 7) << 3;

    const int qrow = qt * 128 + wq * 32 + lq;
    const uint16_t* qp = qf + base + (size_t)qrow * DOUT;
    f16x8 qv[4];
    #pragma unroll
    for (int dsub = 0; dsub < 4; ++dsub)
        qv[dsub] = *(const f16x8*)(qp + dsub * 16 + L * 8);

    f32x16 Zv;
    #pragma unroll
    for (int r = 0; r < 16; ++r) Zv[r] = 0.f;
    f32x16 Oa[2] = {Zv, Zv};
    float m_run = -INFINITY, l_run = 0.f;

    auto qk_step = [&](const char* kb2, f32x16* dst) {
        #pragma unroll
        for (int ks = 0; ks < 2; ++ks) {
            f32x16 s = Zv;
            #pragma unroll
            for (int dsub = 0; dsub < 4; ++dsub) {
                const uint32_t off = (uint32_t)(((ks * 4 + dsub) << 10) + (l << 4));
                const f16x8 kfr = *(const f16x8*)(kb2 + off);
                s = mfma32h(kfr, qv[dsub], s);
            }
            dst[ks] = s;
        }
    };

    gload_lds16(kf + base + (size_t)kr0 * DOUT + do0, smem + c0 * 16);
    gload_lds16(kf + base + (size_t)kr1 * DOUT + do1, smem + c1 * 16);
    gload_lds16(kf + base + (size_t)(64 + kr0) * DOUT + do0, smem + 8192 + c0 * 16);
    gload_lds16(kf + base + (size_t)(64 + kr1) * DOUT + do1, smem + 8192 + c1 * 16);
    gload_lds16(vT + base + (size_t)kr0 * S_LEN + do0, vbufs + c0 * 16);
    gload_lds16(vT + base + (size_t)kr1 * S_LEN + do1, vbufs + c1 * 16);
    asm volatile("s_waitcnt vmcnt(0)" ::: "memory");
    __builtin_amdgcn_s_barrier();
    __builtin_amdgcn_sched_barrier(0);

    f32x16 saA[2], saB[2];
    qk_step(smem, saA);

    auto iter = [&](int kt, f32x16* sa, f32x16* sb) {
        asm volatile("s_waitcnt vmcnt(0)" ::: "memory");
        __builtin_amdgcn_s_barrier();
        __builtin_amdgcn_sched_barrier(0);

        {
            char* __restrict__ kn = smem + (kt & 1) * 8192;
            const int sK = (kt < 30) ? (kt + 2) * 64 : 0;
            gload_lds16(kf + base + (size_t)(sK + kr0) * DOUT + do0, kn + c0 * 16);
            gload_lds16(kf + base + (size_t)(sK + kr1) * DOUT + do1, kn + c1 * 16);
            char* __restrict__ vn = vbufs + ((kt + 1) & 1) * 8192;
            const int sV = (kt < 31) ? (kt + 1) * 64 : 0;
            gload_lds16(vT + base + (size_t)kr0 * S_LEN + sV + do0, vn + c0 * 16);
            gload_lds16(vT + base + (size_t)kr1 * S_LEN + sV + do1, vn + c1 * 16);
        }

        qk_step(smem + ((kt + 1) & 1) * 8192, sb);

        float mx[16];
        #pragma unroll
        for (int r = 0; r < 16; ++r) mx[r] = fmaxf(sa[0][r], sa[1][r]);
        #pragma unroll
        for (int st = 8; st >= 1; st >>= 1)
            #pragma unroll
            for (int r = 0; r < st; ++r) mx[r] = fmaxf(mx[r], mx[r + st]);
        float pmax = mx[0];
        pmax = fmaxf(pmax, __shfl_xor(pmax, 32));

        if (!__all(pmax - m_run <= 8.f)) {
            const float m_new = fmaxf(m_run, pmax);
            const float alpha = __builtin_amdgcn_exp2f(m_run - m_new);
            m_run = m_new;
            #pragma unroll
            for (int r = 0; r < 16; ++r) { Oa[0][r] *= alpha; Oa[1][r] *= alpha; }
            l_run *= alpha;
        }

        #pragma unroll
        for (int ks = 0; ks < 2; ++ks)
            #pragma unroll
            for (int r = 0; r < 16; ++r)
                sa[ks][r] = __builtin_amdgcn_exp2f(sa[ks][r] - m_run);

        float sm[16];
        #pragma unroll
        for (int r = 0; r < 16; ++r) sm[r] = sa[0][r] + sa[1][r];
        #pragma unroll
        for (int st = 8; st >= 1; st >>= 1)
            #pragma unroll
            for (int r = 0; r < st; ++r) sm[r] += sm[r + st];
        float lsum = sm[0];
        lsum += __shfl_xor(lsum, 32);
        l_run += lsum;

        f16x8 pfrag[4];
        #pragma unroll
        for (int ks = 0; ks < 2; ++ks) {
            uint32_t a0 = cvt_pkrtz_f16(sa[ks][0], sa[ks][1]);
            uint32_t a1 = cvt_pkrtz_f16(sa[ks][2], sa[ks][3]);
            uint32_t a2 = cvt_pkrtz_f16(sa[ks][4], sa[ks][5]);
            uint32_t a3 = cvt_pkrtz_f16(sa[ks][6], sa[ks][7]);
            asm volatile("v_permlane32_swap_b32 %0, %1" : "+v"(a0), "+v"(a2));
            asm volatile("v_permlane32_swap_b32 %0, %1" : "+v"(a1), "+v"(a3));
            union { uint32_t w[4]; f16x8 v; } u;
            u.w[0] = a0; u.w[1] = a1; u.w[2] = a2; u.w[3] = a3;
            pfrag[2 * ks] = u.v;
            uint32_t b0 = cvt_pkrtz_f16(sa[ks][8],  sa[ks][9]);
            uint32_t b1 = cvt_pkrtz_f16(sa[ks][10], sa[ks][11]);
            uint32_t b2 = cvt_pkrtz_f16(sa[ks][12], sa[ks][13]);
            uint32_t b3 = cvt_pkrtz_f16(sa[ks][14], sa[ks][15]);
            asm volatile("v_permlane32_swap_b32 %0, %1" : "+v"(b0), "+v"(b2));
            asm volatile("v_permlane32_swap_b32 %0, %1" : "+v"(b1), "+v"(b3));
            union { uint32_t w[4]; f16x8 v; } u2;
            u2.w[0] = b0; u2.w[1] = b1; u2.w[2] = b2; u2.w[3] = b3;
            pfrag[2 * ks + 1] = u2.v;
        }

        const char* __restrict__ vb = vbufs + (kt & 1) * 8192;
        __builtin_amdgcn_s_setprio(1);
        #pragma unroll
        for (int dh = 0; dh < 2; ++dh) {
            #pragma unroll
            for (int kc = 0; kc < 4; ++kc) {
                const uint32_t off = (uint32_t)(((dh * 4 + kc) << 10) + (l << 4));
                const f16x8 vv = *(const f16x8*)(vb + off);
                Oa[dh] = mfma32h(vv, pfrag[kc], Oa[dh]);
            }
        }
        __builtin_amdgcn_s_setprio(0);
    };

    for (int kt2 = 0; kt2 < 16; ++kt2) {
        iter(2 * kt2,     saA, saB);
        iter(2 * kt2 + 1, saB, saA);
    }
    asm volatile("s_waitcnt vmcnt(0)" ::: "memory");

    const int b = bh >> 3, hh = bh & 7;
    const float li = 1.f / l_run;
    const int srow = qt * 128 + wq * 32 + lq;
    const size_t rbase = ((size_t)b * S_LEN + srow) * (NH * DOUT) + hh * DOUT;
    #pragma unroll
    for (int dh = 0; dh < 2; ++dh) {
        #pragma unroll
        for (int rq = 0; rq < 4; ++rq) {
            const int d0 = dh * 32 + rq * 8 + L * 4;
            uint2 val;
            val.x = cvt_pk_bf16(Oa[dh][rq * 4 + 0] * li, Oa[dh][rq * 4 + 1] * li);
            val.y = cvt_pk_bf16(Oa[dh][rq * 4 + 2] * li, Oa[dh][rq * 4 + 3] * li);
            *(uint2*)(oc + rbase + d0) = val;
        }
    }
}

// ---------------------------------------------------------------------------
// Kernel 5: output projection out = o_concat[8192x512] @ wo[512x64], fp32 out.
// ---------------------------------------------------------------------------
__global__ __launch_bounds__(256) void oproj(
    const uint16_t* __restrict__ oc, const uint16_t* __restrict__ woT,
    float* __restrict__ out)
{
    const int mt = blockIdx.x;
    const int tid = threadIdx.x;
    const int l = tid & 63, w = tid >> 6;
    const int g = l >> 4, lm = l & 15;
    const int m0 = mt * 64 + w * 16;
    const f32x4 Z = {0.f, 0.f, 0.f, 0.f};
    f32x4 acc[4] = {Z, Z, Z, Z};
    const uint16_t* __restrict__ arow = oc + (size_t)(m0 + lm) * (NH * DOUT);
    for (int kc = 0; kc < 16; ++kc) {
        const bf16x8 a = *(const bf16x8*)(arow + kc * 32 + g * 8);
        #pragma unroll
        for (int nt = 0; nt < 4; ++nt) {
            const bf16x8 bfr = *(const bf16x8*)(woT + (size_t)(nt * 16 + lm) * (NH * DOUT) + kc * 32 + g * 8);
            acc[nt] = mfma16(a, bfr, acc[nt]);
        }
    }
    #pragma unroll
    for (int nt = 0; nt < 4; ++nt)
        #pragma unroll
        for (int j = 0; j < 4; ++j)
            out[(size_t)(m0 + 4 * g + j) * DOUT + nt * 16 + lm] = acc[nt][j];
}

// ---------------------------------------------------------------------------
extern "C" void kernel_launch(void* const* d_in, const int* in_sizes, int n_in,
                              void* d_out, int out_size, void* d_ws, size_t ws_size,
                              hipStream_t stream) {
    const float* x  = (const float*)d_in[0];
    const float* w  = (const float*)d_in[1];
    const float* wo = (const float*)d_in[2];
    float* out = (float*)d_out;

    char* ws = (char*)d_ws;
    uint16_t* qf   = (uint16_t*)(ws);              // [B*H][S][64] fp16, 8 MB
    uint16_t* kf   = (uint16_t*)(ws + 8388608);    // fp16, 8 MB
    uint16_t* vT   = (uint16_t*)(ws + 16777216);   // [B*H][64][S] fp16, 8 MB
    uint16_t* xhi  = (uint16_t*)(ws + 25165824);   // bf16, 8 MB
    uint16_t* xlo  = (uint16_t*)(ws + 33554432);   // bf16, 8 MB
    uint16_t* whiT = (uint16_t*)(ws + 41943040);   // [1536][512] bf16
    uint16_t* wloT = (uint16_t*)(ws + 43515904);
    uint16_t* woT  = (uint16_t*)(ws + 45088768);   // 65536 B
    // oc aliases xhi (dead after gemm_qkv; split_x rewrites it every call).
    uint16_t* oc   = xhi;

    hipLaunchKernelGGL(prep_w, dim3(200), dim3(256), 0, stream, w, wo, whiT, wloT, woT);
    hipLaunchKernelGGL(split_x, dim3(2048), dim3(256), 0, stream, x, xhi, xlo);
    hipLaunchKernelGGL(gemm_qkv, dim3(768), dim3(256), 0, stream,
                       xhi, xlo, whiT, wloT, qf, kf, vT);
    hipLaunchKernelGGL(attn_fwd, dim3(512), dim3(256), 0, stream,
                       qf, kf, vT, oc);
    hipLaunchKernelGGL(oproj, dim3(128), dim3(256), 0, stream, oc, woT, out);
}